// Round 12
// baseline (924.226 us; speedup 1.0000x reference)
//
#include <hip/hip_runtime.h>

typedef unsigned short u16;
typedef short s16x8 __attribute__((ext_vector_type(8)));
typedef float f32x4 __attribute__((ext_vector_type(4)));

__device__ inline u16 f2bf(float f) {
    unsigned u = __float_as_uint(f);
    u += 0x7FFF + ((u >> 16) & 1);
    return (u16)(u >> 16);
}
__device__ inline float bf2f(u16 h) {
    return __uint_as_float((unsigned)h << 16);
}

__device__ inline f32x4 mfma16(s16x8 a, s16x8 b, f32x4 c) {
    return __builtin_amdgcn_mfma_f32_16x16x32_bf16(a, b, c, 0, 0, 0);
}

// async global->LDS, 16B per lane. LDS dest is wave-uniform base + lane*16.
__device__ __forceinline__ void gl16(const u16* g, u16* l) {
    __builtin_amdgcn_global_load_lds(
        (const __attribute__((address_space(1))) void*)g,
        (__attribute__((address_space(3))) void*)l, 16, 0, 0);
}

// LDS-tiled weight transpose+convert, all matrices in one launch.
__global__ __launch_bounds__(256) void tcvt_all(
    const float* __restrict__ Wq, const float* __restrict__ Wk,
    const float* __restrict__ Wv, const float* __restrict__ Wo,
    const float* __restrict__ W1, const float* __restrict__ W2,
    u16* __restrict__ wT) {
    __shared__ float tile[32][33];
    int bid = blockIdx.x;
    const float* src;
    u16* dst;
    int K, N, tk, tn;
    if (bid < 576) {  // 4 x 144 tiles of 384x384
        int m = bid / 144, t = bid - m * 144;
        src = m == 0 ? Wq : m == 1 ? Wk : m == 2 ? Wv : Wo;
        dst = wT + m * 147456;
        K = 384; N = 384; tk = t / 12; tn = t - (t / 12) * 12;
    } else if (bid < 1152) {  // W1: 384x1536, 12 tk x 48 tn
        int t = bid - 576;
        src = W1; dst = wT + 589824;
        K = 384; N = 1536; tk = t / 48; tn = t - (t / 48) * 48;
    } else {  // W2: 1536x384, 48 tk x 12 tn
        int t = bid - 1152;
        src = W2; dst = wT + 1179648;
        K = 1536; N = 384; tk = t / 12; tn = t - (t / 12) * 12;
    }
    int tx = threadIdx.x & 31, ty = threadIdx.x >> 5;  // 32 x 8
#pragma unroll
    for (int p = 0; p < 4; ++p) {
        int k = tk * 32 + ty + p * 8;
        tile[ty + p * 8][tx] = src[(size_t)k * N + tn * 32 + tx];
    }
    __syncthreads();
#pragma unroll
    for (int p = 0; p < 4; ++p) {
        int n = tn * 32 + ty + p * 8;
        dst[(size_t)n * K + tk * 32 + tx] = f2bf(tile[tx][ty + p * 8]);
    }
}

// LayerNorm over rows of 384 fp32 -> bf16. One wave per row, 4 rows/block.
__global__ __launch_bounds__(256) void ln_kernel(const float* __restrict__ x,
                                                 const float* __restrict__ g,
                                                 const float* __restrict__ be,
                                                 u16* __restrict__ out) {
    int lane = threadIdx.x & 63;
    int w = threadIdx.x >> 6;
    int row = blockIdx.x * 4 + w;
    const float* xr = x + (size_t)row * 384;
    float v[6];
    float s = 0.f, sq = 0.f;
#pragma unroll
    for (int i = 0; i < 6; ++i) {
        v[i] = xr[i * 64 + lane];
        s += v[i];
        sq += v[i] * v[i];
    }
#pragma unroll
    for (int m = 1; m < 64; m <<= 1) {
        s += __shfl_xor(s, m);
        sq += __shfl_xor(sq, m);
    }
    float mu = s * (1.0f / 384.0f);
    float var = sq * (1.0f / 384.0f) - mu * mu;
    float rstd = rsqrtf(var + 1e-5f);
    u16* orow = out + (size_t)row * 384;
#pragma unroll
    for (int i = 0; i < 6; ++i) {
        int col = i * 64 + lane;
        orow[col] = f2bf((v[i] - mu) * rstd * g[col] + be[col]);
    }
}

// LayerNorm, bf16 input rows of 384 -> bf16. One wave/row, 48 active lanes x8.
__global__ __launch_bounds__(256) void ln_bf16_kernel(const u16* __restrict__ x,
                                                      const float* __restrict__ g,
                                                      const float* __restrict__ be,
                                                      u16* __restrict__ out) {
    int lane = threadIdx.x & 63;
    int w = threadIdx.x >> 6;
    int row = blockIdx.x * 4 + w;
    const u16* xr = x + (size_t)row * 384;
    bool act = lane < 48;
    float v[8];
    float s = 0.f, sq = 0.f;
    if (act) {
        s16x8 t = *(const s16x8*)&xr[lane * 8];
#pragma unroll
        for (int j = 0; j < 8; ++j) {
            v[j] = bf2f((u16)t[j]);
            s += v[j];
            sq += v[j] * v[j];
        }
    }
#pragma unroll
    for (int m = 1; m < 64; m <<= 1) {
        s += __shfl_xor(s, m);
        sq += __shfl_xor(sq, m);
    }
    float mu = s * (1.0f / 384.0f);
    float var = sq * (1.0f / 384.0f) - mu * mu;
    float rstd = rsqrtf(var + 1e-5f);
    if (act) {
        float4 g0 = *(const float4*)&g[lane * 8];
        float4 g1 = *(const float4*)&g[lane * 8 + 4];
        float4 b0 = *(const float4*)&be[lane * 8];
        float4 b1 = *(const float4*)&be[lane * 8 + 4];
        float gg[8] = {g0.x, g0.y, g0.z, g0.w, g1.x, g1.y, g1.z, g1.w};
        float bb[8] = {b0.x, b0.y, b0.z, b0.w, b1.x, b1.y, b1.z, b1.w};
        u16* orow = out + (size_t)row * 384 + lane * 8;
#pragma unroll
        for (int j = 0; j < 8; ++j)
            orow[j] = f2bf((v[j] - mu) * rstd * gg[j] + bb[j]);
    }
}

// bf16 GEMM, R6 loop, 3 blocks/CU (launch_bounds(512,6): 48 KB LDS x3 = 144
// <= 160; VGPR cap 85 > measured 60). No setprio (T5 is ~0/negative in
// lockstep loops, m190). 256x128 tile, BK=32, 8 waves (4x2), wave 64x64,
// proven involution swizzle (0 conflicts).
template <int BIAS, int RELU, int RES, int RESBF, int OBF16, int NBN>
__global__ __launch_bounds__(512, 6) void gemm_kernel(const u16* __restrict__ A,
                                                      const u16* __restrict__ Bt,
                                                      const float* __restrict__ bias,
                                                      const void* __restrict__ res,
                                                      void* __restrict__ out,
                                                      int M, int N, int K) {
    __shared__ u16 La[2][256 * 32];
    __shared__ u16 Lb[2][128 * 32];
    int tid = threadIdx.x;
    int lane = tid & 63, w = tid >> 6;   // 8 waves
    int wm = w >> 1, wn = w & 1;         // 4 x 2 wave grid
    int lr = lane & 15, lg = lane >> 4;

    int nwg = gridDim.x;
    int q = nwg >> 3, r = nwg & 7;
    int xcd = blockIdx.x & 7, lin = blockIdx.x >> 3;
    int wg = (xcd < r ? xcd * (q + 1) : r * (q + 1) + (xcd - r) * q) + lin;
    int bx = wg % NBN, by = wg / NBN;
    int m0 = by * 256, n0 = bx * 128;

    int rsub = lane >> 2;
    int gslot = ((lane & 3) ^ ((lane >> 3) & 3)) * 8;
    const u16* pa[2];
    const u16* pb1;
#pragma unroll
    for (int i = 0; i < 2; ++i)
        pa[i] = A + (size_t)(m0 + w * 32 + i * 16 + rsub) * K + gslot;
    pb1 = Bt + (size_t)(n0 + w * 16 + rsub) * K + gslot;

    f32x4 acc[4][4];
    f32x4 zero = {0.f, 0.f, 0.f, 0.f};
#pragma unroll
    for (int mt = 0; mt < 4; ++mt)
#pragma unroll
        for (int nt = 0; nt < 4; ++nt) acc[mt][nt] = zero;

    int sel = (lg ^ ((lr >> 1) & 3)) << 3;
    int nt_steps = K >> 5;

#define STAGE(t, bsel)                                  \
    do {                                                \
        int kc = (t) << 5;                              \
        gl16(pa[0] + kc, &La[bsel][(w * 32) * 32]);     \
        gl16(pa[1] + kc, &La[bsel][(w * 32 + 16) * 32]);\
        gl16(pb1 + kc, &Lb[bsel][(w * 16) * 32]);       \
    } while (0)

    STAGE(0, 0);

    for (int t = 0; t < nt_steps; ++t) {
        asm volatile("s_waitcnt vmcnt(0)" ::: "memory");
        __builtin_amdgcn_s_barrier();
        asm volatile("" ::: "memory");
        if (t + 1 < nt_steps) STAGE(t + 1, (t + 1) & 1);
        const u16* lab = La[t & 1];
        const u16* lbb = Lb[t & 1];
        s16x8 af[4], bfr[4];
#pragma unroll
        for (int mt = 0; mt < 4; ++mt)
            af[mt] = *(const s16x8*)&lab[(wm * 64 + mt * 16 + lr) * 32 + sel];
#pragma unroll
        for (int nt = 0; nt < 4; ++nt)
            bfr[nt] = *(const s16x8*)&lbb[(wn * 64 + nt * 16 + lr) * 32 + sel];
#pragma unroll
        for (int mt = 0; mt < 4; ++mt)
#pragma unroll
            for (int nt = 0; nt < 4; ++nt)
                acc[mt][nt] = mfma16(af[mt], bfr[nt], acc[mt][nt]);
    }
#undef STAGE

#pragma unroll
    for (int mt = 0; mt < 4; ++mt) {
#pragma unroll
        for (int nt = 0; nt < 4; ++nt) {
            int m_base = m0 + wm * 64 + mt * 16 + lg * 4;
            int n = n0 + wn * 64 + nt * 16 + lr;
            float bv = BIAS ? bias[n] : 0.0f;
#pragma unroll
            for (int r2 = 0; r2 < 4; ++r2) {
                size_t idx = (size_t)(m_base + r2) * N + n;
                float val = acc[mt][nt][r2] + bv;
                if (RES) {
                    if (RESBF)
                        val += bf2f(((const u16*)res)[idx]);
                    else
                        val += ((const float*)res)[idx];
                }
                if (RELU) val = fmaxf(val, 0.0f);
                if (OBF16)
                    ((u16*)out)[idx] = f2bf(val);
                else
                    ((float*)out)[idx] = val;
            }
        }
    }
}

// Causal attention (R11 structure), LDS right-sized by template: qt0 kernel
// (q<128, K/V t<128) uses 69 KB -> 2 blocks/CU; qt1 full-size 135 KB.
template <int QT0>
__global__ __launch_bounds__(512) void attn_kernel(const u16* __restrict__ qkv,
                                                   u16* __restrict__ aout) {
    constexpr int NT = QT0 ? 8 : 16;      // K-column tiles
    constexpr int TL = NT * 16;           // K/V length
    constexpr int VTW = TL + 8;           // padded t-row
    constexpr int NSTG = QT0 ? 2 : 4;     // staging passes
    __shared__ u16 Kl[TL * 72];           // K rows [t][d], pad 64->72
    __shared__ u16 Vt[64 * VTW];          // V transposed [d][t]
    __shared__ u16 Pl[8 * 16 * VTW];      // per-wave P [16][t]
    int h = blockIdx.x, b = blockIdx.y;
    int tid = threadIdx.x, lane = tid & 63, w = tid >> 6;
    int lr = lane & 15, lg = lane >> 4;
    const u16* qb = qkv + (size_t)b * 256 * 1152;

#pragma unroll
    for (int i = 0; i < NSTG; ++i) {
        int c = tid + i * 512;
        int t = c >> 3, dch = c & 7;
        *(int4*)&Kl[t * 72 + dch * 8] =
            *(const int4*)(qb + (size_t)t * 1152 + 384 + h * 64 + dch * 8);
        union { int4 v; u16 u[8]; } vv;
        vv.v = *(const int4*)(qb + (size_t)t * 1152 + 768 + h * 64 + dch * 8);
#pragma unroll
        for (int j = 0; j < 8; ++j) Vt[(dch * 8 + j) * VTW + t] = vv.u[j];
    }

    const int q0 = QT0 ? 0 : 128;
    const u16* qrow = qb + (size_t)(q0 + w * 16 + lr) * 1152 + h * 64;
    s16x8 qf0 = *(const s16x8*)(qrow + lg * 8);
    s16x8 qf1 = *(const s16x8*)(qrow + 32 + lg * 8);

    __syncthreads();

    f32x4 zero = {0.f, 0.f, 0.f, 0.f};
    f32x4 s[NT];
#pragma unroll
    for (int nt = 0; nt < NT; ++nt) s[nt] = zero;
#pragma unroll
    for (int nt = 0; nt < NT; ++nt) {
        s16x8 kf0 = *(const s16x8*)&Kl[(nt * 16 + lr) * 72 + lg * 8];
        s16x8 kf1 = *(const s16x8*)&Kl[(nt * 16 + lr) * 72 + 32 + lg * 8];
        s[nt] = mfma16(qf0, kf0, s[nt]);
        s[nt] = mfma16(qf1, kf1, s[nt]);
    }

    int ib = q0 + w * 16 + lg * 4;
    float mx[4] = {-1e30f, -1e30f, -1e30f, -1e30f};
#pragma unroll
    for (int nt = 0; nt < NT; ++nt) {
        int jg = nt * 16 + lr;
#pragma unroll
        for (int r = 0; r < 4; ++r) {
            float val = s[nt][r] * 0.125f;
            val = (jg <= ib + r) ? val : -1e30f;
            s[nt][r] = val;
            mx[r] = fmaxf(mx[r], val);
        }
    }
#pragma unroll
    for (int r = 0; r < 4; ++r) {
        mx[r] = fmaxf(mx[r], __shfl_xor(mx[r], 1));
        mx[r] = fmaxf(mx[r], __shfl_xor(mx[r], 2));
        mx[r] = fmaxf(mx[r], __shfl_xor(mx[r], 4));
        mx[r] = fmaxf(mx[r], __shfl_xor(mx[r], 8));
    }
    float rs[4] = {0.f, 0.f, 0.f, 0.f};
#pragma unroll
    for (int nt = 0; nt < NT; ++nt) {
#pragma unroll
        for (int r = 0; r < 4; ++r) {
            float p = __expf(s[nt][r] - mx[r]);
            s[nt][r] = p;
            rs[r] += p;
        }
    }
#pragma unroll
    for (int r = 0; r < 4; ++r) {
        rs[r] += __shfl_xor(rs[r], 1);
        rs[r] += __shfl_xor(rs[r], 2);
        rs[r] += __shfl_xor(rs[r], 4);
        rs[r] += __shfl_xor(rs[r], 8);
    }
    // per-wave P through LDS (no barrier: same-wave DS ordering)
    u16* Pw = &Pl[w * 16 * VTW];
#pragma unroll
    for (int nt = 0; nt < NT; ++nt)
#pragma unroll
        for (int r = 0; r < 4; ++r)
            Pw[(lg * 4 + r) * VTW + nt * 16 + lr] = f2bf(s[nt][r]);

    f32x4 o[4];
#pragma unroll
    for (int nt = 0; nt < 4; ++nt) o[nt] = zero;
#pragma unroll
    for (int kc = 0; kc < NT / 2; ++kc) {
        s16x8 pf = *(const s16x8*)&Pw[lr * VTW + kc * 32 + lg * 8];
#pragma unroll
        for (int nt = 0; nt < 4; ++nt) {
            s16x8 vf = *(const s16x8*)&Vt[(nt * 16 + lr) * VTW + kc * 32 + lg * 8];
            o[nt] = mfma16(pf, vf, o[nt]);
        }
    }
    float inv[4];
#pragma unroll
    for (int r = 0; r < 4; ++r) inv[r] = 1.0f / rs[r];
    u16* ob = aout + (size_t)(b * 256 + q0 + w * 16) * 384 + h * 64;
#pragma unroll
    for (int nt = 0; nt < 4; ++nt)
#pragma unroll
        for (int r = 0; r < 4; ++r)
            ob[(size_t)(lg * 4 + r) * 384 + nt * 16 + lr] = f2bf(o[nt][r] * inv[r]);
}

extern "C" void kernel_launch(void* const* d_in, const int* in_sizes, int n_in,
                              void* d_out, int out_size, void* d_ws, size_t ws_size,
                              hipStream_t stream) {
    const float* x   = (const float*)d_in[0];
    const float* Wk  = (const float*)d_in[1];
    const float* Wq  = (const float*)d_in[2];
    const float* Wv  = (const float*)d_in[3];
    const float* Wo  = (const float*)d_in[4];
    const float* bo  = (const float*)d_in[5];
    const float* W1  = (const float*)d_in[6];
    const float* b1  = (const float*)d_in[7];
    const float* W2  = (const float*)d_in[8];
    const float* b2  = (const float*)d_in[9];
    const float* g1  = (const float*)d_in[10];
    const float* be1 = (const float*)d_in[11];
    const float* g2  = (const float*)d_in[12];
    const float* be2 = (const float*)d_in[13];

    char* ws = (char*)d_ws;
    u16* hbuf = (u16*)(ws + 0);            // 25165824 B (h1, later h2)
    u16* qkv  = (u16*)(ws + 25165824);     // 75497472 B
    u16* ao   = (u16*)(ws + 100663296);    // 25165824 B
    u16* x1   = (u16*)(ws + 125829120);    // 25165824 B (bf16)
    u16* ubuf = (u16*)(ws + 25165824);     // 100663296 B (aliases qkv+ao, both dead)
    u16* wT   = (u16*)(ws + 150994944);    // 3538944 B of bf16 weights
    u16* wqkvT = wT;                  // [1152][384]: q 0-383, k 384-767, v 768-1151
    u16* woT   = wT + 442368;         // [384][384]
    u16* w1T   = woT + 147456;        // [1536][384]
    u16* w2T   = w1T + 589824;        // [384][1536]

    tcvt_all<<<1728, 256, 0, stream>>>(Wq, Wk, Wv, Wo, W1, W2, wT);

    // h1 = LN(x)
    ln_kernel<<<8192, 256, 0, stream>>>(x, g1, be1, hbuf);
    // qkv = h1 @ [Wq|Wk|Wv]
    gemm_kernel<0, 0, 0, 0, 1, 9><<<1152, 512, 0, stream>>>(
        hbuf, wqkvT, nullptr, nullptr, qkv, 32768, 1152, 384);
    // attention (causal split: qt0 does half the K/V work, 2 blocks/CU)
    attn_kernel<1><<<dim3(6, 128), 512, 0, stream>>>(qkv, ao);
    attn_kernel<0><<<dim3(6, 128), 512, 0, stream>>>(qkv, ao);
    // x1 = x + ao @ Wo + bo   (bf16 out)
    gemm_kernel<1, 0, 1, 0, 1, 3><<<384, 512, 0, stream>>>(
        ao, woT, bo, x, x1, 32768, 384, 384);
    // h2 = LN(x1)
    ln_bf16_kernel<<<8192, 256, 0, stream>>>(x1, g2, be2, hbuf);
    // u = relu(h2 @ W1 + b1)
    gemm_kernel<1, 1, 0, 0, 1, 12><<<1536, 512, 0, stream>>>(
        hbuf, w1T, b1, nullptr, ubuf, 32768, 1536, 384);
    // out = x1 + u @ W2 + b2  (fp32 out, bf16 res)
    gemm_kernel<1, 0, 1, 1, 0, 3><<<384, 512, 0, stream>>>(
        ubuf, w2T, b2, x1, (float*)d_out, 32768, 384, 1536);
}

// Round 13
// 245.062 us; speedup vs baseline: 3.7714x; 3.7714x over previous
//
#include <hip/hip_runtime.h>

typedef unsigned short u16;
typedef short s16x8 __attribute__((ext_vector_type(8)));
typedef float f32x4 __attribute__((ext_vector_type(4)));

__device__ inline u16 f2bf(float f) {
    unsigned u = __float_as_uint(f);
    u += 0x7FFF + ((u >> 16) & 1);
    return (u16)(u >> 16);
}
__device__ inline float bf2f(u16 h) {
    return __uint_as_float((unsigned)h << 16);
}

__device__ inline f32x4 mfma16(s16x8 a, s16x8 b, f32x4 c) {
    return __builtin_amdgcn_mfma_f32_16x16x32_bf16(a, b, c, 0, 0, 0);
}

// async global->LDS, 16B per lane. LDS dest is wave-uniform base + lane*16.
__device__ __forceinline__ void gl16(const u16* g, u16* l) {
    __builtin_amdgcn_global_load_lds(
        (const __attribute__((address_space(1))) void*)g,
        (__attribute__((address_space(3))) void*)l, 16, 0, 0);
}

// LDS-tiled weight transpose+convert, all matrices in one launch.
__global__ __launch_bounds__(256) void tcvt_all(
    const float* __restrict__ Wq, const float* __restrict__ Wk,
    const float* __restrict__ Wv, const float* __restrict__ Wo,
    const float* __restrict__ W1, const float* __restrict__ W2,
    u16* __restrict__ wT) {
    __shared__ float tile[32][33];
    int bid = blockIdx.x;
    const float* src;
    u16* dst;
    int K, N, tk, tn;
    if (bid < 576) {  // 4 x 144 tiles of 384x384
        int m = bid / 144, t = bid - m * 144;
        src = m == 0 ? Wq : m == 1 ? Wk : m == 2 ? Wv : Wo;
        dst = wT + m * 147456;
        K = 384; N = 384; tk = t / 12; tn = t - (t / 12) * 12;
    } else if (bid < 1152) {  // W1: 384x1536, 12 tk x 48 tn
        int t = bid - 576;
        src = W1; dst = wT + 589824;
        K = 384; N = 1536; tk = t / 48; tn = t - (t / 48) * 48;
    } else {  // W2: 1536x384, 48 tk x 12 tn
        int t = bid - 1152;
        src = W2; dst = wT + 1179648;
        K = 1536; N = 384; tk = t / 12; tn = t - (t / 12) * 12;
    }
    int tx = threadIdx.x & 31, ty = threadIdx.x >> 5;  // 32 x 8
#pragma unroll
    for (int p = 0; p < 4; ++p) {
        int k = tk * 32 + ty + p * 8;
        tile[ty + p * 8][tx] = src[(size_t)k * N + tn * 32 + tx];
    }
    __syncthreads();
#pragma unroll
    for (int p = 0; p < 4; ++p) {
        int n = tn * 32 + ty + p * 8;
        dst[(size_t)n * K + tk * 32 + tx] = f2bf(tile[tx][ty + p * 8]);
    }
}

// LayerNorm over rows of 384 fp32 -> bf16. One wave per row, 4 rows/block.
__global__ __launch_bounds__(256) void ln_kernel(const float* __restrict__ x,
                                                 const float* __restrict__ g,
                                                 const float* __restrict__ be,
                                                 u16* __restrict__ out) {
    int lane = threadIdx.x & 63;
    int w = threadIdx.x >> 6;
    int row = blockIdx.x * 4 + w;
    const float* xr = x + (size_t)row * 384;
    float v[6];
    float s = 0.f, sq = 0.f;
#pragma unroll
    for (int i = 0; i < 6; ++i) {
        v[i] = xr[i * 64 + lane];
        s += v[i];
        sq += v[i] * v[i];
    }
#pragma unroll
    for (int m = 1; m < 64; m <<= 1) {
        s += __shfl_xor(s, m);
        sq += __shfl_xor(sq, m);
    }
    float mu = s * (1.0f / 384.0f);
    float var = sq * (1.0f / 384.0f) - mu * mu;
    float rstd = rsqrtf(var + 1e-5f);
    u16* orow = out + (size_t)row * 384;
#pragma unroll
    for (int i = 0; i < 6; ++i) {
        int col = i * 64 + lane;
        orow[col] = f2bf((v[i] - mu) * rstd * g[col] + be[col]);
    }
}

// LayerNorm, bf16 input rows of 384 -> bf16. One wave/row, 48 active lanes x8.
__global__ __launch_bounds__(256) void ln_bf16_kernel(const u16* __restrict__ x,
                                                      const float* __restrict__ g,
                                                      const float* __restrict__ be,
                                                      u16* __restrict__ out) {
    int lane = threadIdx.x & 63;
    int w = threadIdx.x >> 6;
    int row = blockIdx.x * 4 + w;
    const u16* xr = x + (size_t)row * 384;
    bool act = lane < 48;
    float v[8];
    float s = 0.f, sq = 0.f;
    if (act) {
        s16x8 t = *(const s16x8*)&xr[lane * 8];
#pragma unroll
        for (int j = 0; j < 8; ++j) {
            v[j] = bf2f((u16)t[j]);
            s += v[j];
            sq += v[j] * v[j];
        }
    }
#pragma unroll
    for (int m = 1; m < 64; m <<= 1) {
        s += __shfl_xor(s, m);
        sq += __shfl_xor(sq, m);
    }
    float mu = s * (1.0f / 384.0f);
    float var = sq * (1.0f / 384.0f) - mu * mu;
    float rstd = rsqrtf(var + 1e-5f);
    if (act) {
        float4 g0 = *(const float4*)&g[lane * 8];
        float4 g1 = *(const float4*)&g[lane * 8 + 4];
        float4 b0 = *(const float4*)&be[lane * 8];
        float4 b1 = *(const float4*)&be[lane * 8 + 4];
        float gg[8] = {g0.x, g0.y, g0.z, g0.w, g1.x, g1.y, g1.z, g1.w};
        float bb[8] = {b0.x, b0.y, b0.z, b0.w, b1.x, b1.y, b1.z, b1.w};
        u16* orow = out + (size_t)row * 384 + lane * 8;
#pragma unroll
        for (int j = 0; j < 8; ++j)
            orow[j] = f2bf((v[j] - mu) * rstd * gg[j] + bb[j]);
    }
}

// bf16 GEMM = exact R11-bench config (best measured, 249 us): 256x128 tile,
// BK=32, 8 waves (4x2), wave 64x64, dbuf 48 KB LDS, launch_bounds(512,4)
// (VGPR 60, no spills — (512,6) forced VGPR=40 and spilled 1 GB, R12),
// setprio around MFMA, proven involution swizzle (0 conflicts).
template <int BIAS, int RELU, int RES, int RESBF, int OBF16, int NBN>
__global__ __launch_bounds__(512, 4) void gemm_kernel(const u16* __restrict__ A,
                                                      const u16* __restrict__ Bt,
                                                      const float* __restrict__ bias,
                                                      const void* __restrict__ res,
                                                      void* __restrict__ out,
                                                      int M, int N, int K) {
    __shared__ u16 La[2][256 * 32];
    __shared__ u16 Lb[2][128 * 32];
    int tid = threadIdx.x;
    int lane = tid & 63, w = tid >> 6;   // 8 waves
    int wm = w >> 1, wn = w & 1;         // 4 x 2 wave grid
    int lr = lane & 15, lg = lane >> 4;

    int nwg = gridDim.x;
    int q = nwg >> 3, r = nwg & 7;
    int xcd = blockIdx.x & 7, lin = blockIdx.x >> 3;
    int wg = (xcd < r ? xcd * (q + 1) : r * (q + 1) + (xcd - r) * q) + lin;
    int bx = wg % NBN, by = wg / NBN;
    int m0 = by * 256, n0 = bx * 128;

    int rsub = lane >> 2;
    int gslot = ((lane & 3) ^ ((lane >> 3) & 3)) * 8;
    const u16* pa[2];
    const u16* pb1;
#pragma unroll
    for (int i = 0; i < 2; ++i)
        pa[i] = A + (size_t)(m0 + w * 32 + i * 16 + rsub) * K + gslot;
    pb1 = Bt + (size_t)(n0 + w * 16 + rsub) * K + gslot;

    f32x4 acc[4][4];
    f32x4 zero = {0.f, 0.f, 0.f, 0.f};
#pragma unroll
    for (int mt = 0; mt < 4; ++mt)
#pragma unroll
        for (int nt = 0; nt < 4; ++nt) acc[mt][nt] = zero;

    int sel = (lg ^ ((lr >> 1) & 3)) << 3;
    int nt_steps = K >> 5;

#define STAGE(t, bsel)                                  \
    do {                                                \
        int kc = (t) << 5;                              \
        gl16(pa[0] + kc, &La[bsel][(w * 32) * 32]);     \
        gl16(pa[1] + kc, &La[bsel][(w * 32 + 16) * 32]);\
        gl16(pb1 + kc, &Lb[bsel][(w * 16) * 32]);       \
    } while (0)

    STAGE(0, 0);

    for (int t = 0; t < nt_steps; ++t) {
        asm volatile("s_waitcnt vmcnt(0)" ::: "memory");
        __builtin_amdgcn_s_barrier();
        asm volatile("" ::: "memory");
        if (t + 1 < nt_steps) STAGE(t + 1, (t + 1) & 1);
        const u16* lab = La[t & 1];
        const u16* lbb = Lb[t & 1];
        s16x8 af[4], bfr[4];
#pragma unroll
        for (int mt = 0; mt < 4; ++mt)
            af[mt] = *(const s16x8*)&lab[(wm * 64 + mt * 16 + lr) * 32 + sel];
#pragma unroll
        for (int nt = 0; nt < 4; ++nt)
            bfr[nt] = *(const s16x8*)&lbb[(wn * 64 + nt * 16 + lr) * 32 + sel];
        __builtin_amdgcn_s_setprio(1);
#pragma unroll
        for (int mt = 0; mt < 4; ++mt)
#pragma unroll
            for (int nt = 0; nt < 4; ++nt)
                acc[mt][nt] = mfma16(af[mt], bfr[nt], acc[mt][nt]);
        __builtin_amdgcn_s_setprio(0);
    }
#undef STAGE

#pragma unroll
    for (int mt = 0; mt < 4; ++mt) {
#pragma unroll
        for (int nt = 0; nt < 4; ++nt) {
            int m_base = m0 + wm * 64 + mt * 16 + lg * 4;
            int n = n0 + wn * 64 + nt * 16 + lr;
            float bv = BIAS ? bias[n] : 0.0f;
#pragma unroll
            for (int r2 = 0; r2 < 4; ++r2) {
                size_t idx = (size_t)(m_base + r2) * N + n;
                float val = acc[mt][nt][r2] + bv;
                if (RES) {
                    if (RESBF)
                        val += bf2f(((const u16*)res)[idx]);
                    else
                        val += ((const float*)res)[idx];
                }
                if (RELU) val = fmaxf(val, 0.0f);
                if (OBF16)
                    ((u16*)out)[idx] = f2bf(val);
                else
                    ((float*)out)[idx] = val;
            }
        }
    }
}

// Causal attention (R11 structure), LDS right-sized by template: qt0 kernel
// (q<128, K/V t<128) uses 69 KB -> 2 blocks/CU; qt1 full-size 135 KB.
template <int QT0>
__global__ __launch_bounds__(512) void attn_kernel(const u16* __restrict__ qkv,
                                                   u16* __restrict__ aout) {
    constexpr int NT = QT0 ? 8 : 16;      // K-column tiles
    constexpr int TL = NT * 16;           // K/V length
    constexpr int VTW = TL + 8;           // padded t-row
    constexpr int NSTG = QT0 ? 2 : 4;     // staging passes
    __shared__ u16 Kl[TL * 72];           // K rows [t][d], pad 64->72
    __shared__ u16 Vt[64 * VTW];          // V transposed [d][t]
    __shared__ u16 Pl[8 * 16 * VTW];      // per-wave P [16][t]
    int h = blockIdx.x, b = blockIdx.y;
    int tid = threadIdx.x, lane = tid & 63, w = tid >> 6;
    int lr = lane & 15, lg = lane >> 4;
    const u16* qb = qkv + (size_t)b * 256 * 1152;

#pragma unroll
    for (int i = 0; i < NSTG; ++i) {
        int c = tid + i * 512;
        int t = c >> 3, dch = c & 7;
        *(int4*)&Kl[t * 72 + dch * 8] =
            *(const int4*)(qb + (size_t)t * 1152 + 384 + h * 64 + dch * 8);
        union { int4 v; u16 u[8]; } vv;
        vv.v = *(const int4*)(qb + (size_t)t * 1152 + 768 + h * 64 + dch * 8);
#pragma unroll
        for (int j = 0; j < 8; ++j) Vt[(dch * 8 + j) * VTW + t] = vv.u[j];
    }

    const int q0 = QT0 ? 0 : 128;
    const u16* qrow = qb + (size_t)(q0 + w * 16 + lr) * 1152 + h * 64;
    s16x8 qf0 = *(const s16x8*)(qrow + lg * 8);
    s16x8 qf1 = *(const s16x8*)(qrow + 32 + lg * 8);

    __syncthreads();

    f32x4 zero = {0.f, 0.f, 0.f, 0.f};
    f32x4 s[NT];
#pragma unroll
    for (int nt = 0; nt < NT; ++nt) s[nt] = zero;
#pragma unroll
    for (int nt = 0; nt < NT; ++nt) {
        s16x8 kf0 = *(const s16x8*)&Kl[(nt * 16 + lr) * 72 + lg * 8];
        s16x8 kf1 = *(const s16x8*)&Kl[(nt * 16 + lr) * 72 + 32 + lg * 8];
        s[nt] = mfma16(qf0, kf0, s[nt]);
        s[nt] = mfma16(qf1, kf1, s[nt]);
    }

    int ib = q0 + w * 16 + lg * 4;
    float mx[4] = {-1e30f, -1e30f, -1e30f, -1e30f};
#pragma unroll
    for (int nt = 0; nt < NT; ++nt) {
        int jg = nt * 16 + lr;
#pragma unroll
        for (int r = 0; r < 4; ++r) {
            float val = s[nt][r] * 0.125f;
            val = (jg <= ib + r) ? val : -1e30f;
            s[nt][r] = val;
            mx[r] = fmaxf(mx[r], val);
        }
    }
#pragma unroll
    for (int r = 0; r < 4; ++r) {
        mx[r] = fmaxf(mx[r], __shfl_xor(mx[r], 1));
        mx[r] = fmaxf(mx[r], __shfl_xor(mx[r], 2));
        mx[r] = fmaxf(mx[r], __shfl_xor(mx[r], 4));
        mx[r] = fmaxf(mx[r], __shfl_xor(mx[r], 8));
    }
    float rs[4] = {0.f, 0.f, 0.f, 0.f};
#pragma unroll
    for (int nt = 0; nt < NT; ++nt) {
#pragma unroll
        for (int r = 0; r < 4; ++r) {
            float p = __expf(s[nt][r] - mx[r]);
            s[nt][r] = p;
            rs[r] += p;
        }
    }
#pragma unroll
    for (int r = 0; r < 4; ++r) {
        rs[r] += __shfl_xor(rs[r], 1);
        rs[r] += __shfl_xor(rs[r], 2);
        rs[r] += __shfl_xor(rs[r], 4);
        rs[r] += __shfl_xor(rs[r], 8);
    }
    // per-wave P through LDS (no barrier: same-wave DS ordering)
    u16* Pw = &Pl[w * 16 * VTW];
#pragma unroll
    for (int nt = 0; nt < NT; ++nt)
#pragma unroll
        for (int r = 0; r < 4; ++r)
            Pw[(lg * 4 + r) * VTW + nt * 16 + lr] = f2bf(s[nt][r]);

    f32x4 o[4];
#pragma unroll
    for (int nt = 0; nt < 4; ++nt) o[nt] = zero;
#pragma unroll
    for (int kc = 0; kc < NT / 2; ++kc) {
        s16x8 pf = *(const s16x8*)&Pw[lr * VTW + kc * 32 + lg * 8];
#pragma unroll
        for (int nt = 0; nt < 4; ++nt) {
            s16x8 vf = *(const s16x8*)&Vt[(nt * 16 + lr) * VTW + kc * 32 + lg * 8];
            o[nt] = mfma16(pf, vf, o[nt]);
        }
    }
    float inv[4];
#pragma unroll
    for (int r = 0; r < 4; ++r) inv[r] = 1.0f / rs[r];
    u16* ob = aout + (size_t)(b * 256 + q0 + w * 16) * 384 + h * 64;
#pragma unroll
    for (int nt = 0; nt < 4; ++nt)
#pragma unroll
        for (int r = 0; r < 4; ++r)
            ob[(size_t)(lg * 4 + r) * 384 + nt * 16 + lr] = f2bf(o[nt][r] * inv[r]);
}

extern "C" void kernel_launch(void* const* d_in, const int* in_sizes, int n_in,
                              void* d_out, int out_size, void* d_ws, size_t ws_size,
                              hipStream_t stream) {
    const float* x   = (const float*)d_in[0];
    const float* Wk  = (const float*)d_in[1];
    const float* Wq  = (const float*)d_in[2];
    const float* Wv  = (const float*)d_in[3];
    const float* Wo  = (const float*)d_in[4];
    const float* bo  = (const float*)d_in[5];
    const float* W1  = (const float*)d_in[6];
    const float* b1  = (const float*)d_in[7];
    const float* W2  = (const float*)d_in[8];
    const float* b2  = (const float*)d_in[9];
    const float* g1  = (const float*)d_in[10];
    const float* be1 = (const float*)d_in[11];
    const float* g2  = (const float*)d_in[12];
    const float* be2 = (const float*)d_in[13];

    char* ws = (char*)d_ws;
    u16* hbuf = (u16*)(ws + 0);            // 25165824 B (h1, later h2)
    u16* qkv  = (u16*)(ws + 25165824);     // 75497472 B
    u16* ao   = (u16*)(ws + 100663296);    // 25165824 B
    u16* x1   = (u16*)(ws + 125829120);    // 25165824 B (bf16)
    u16* ubuf = (u16*)(ws + 25165824);     // 100663296 B (aliases qkv+ao, both dead)
    u16* wT   = (u16*)(ws + 150994944);    // 3538944 B of bf16 weights
    u16* wqkvT = wT;                  // [1152][384]: q 0-383, k 384-767, v 768-1151
    u16* woT   = wT + 442368;         // [384][384]
    u16* w1T   = woT + 147456;        // [1536][384]
    u16* w2T   = w1T + 589824;        // [384][1536]

    tcvt_all<<<1728, 256, 0, stream>>>(Wq, Wk, Wv, Wo, W1, W2, wT);

    // h1 = LN(x)
    ln_kernel<<<8192, 256, 0, stream>>>(x, g1, be1, hbuf);
    // qkv = h1 @ [Wq|Wk|Wv]
    gemm_kernel<0, 0, 0, 0, 1, 9><<<1152, 512, 0, stream>>>(
        hbuf, wqkvT, nullptr, nullptr, qkv, 32768, 1152, 384);
    // attention (qt1 first: long-pole 1-block/CU kernel, then qt0 back-fills)
    attn_kernel<0><<<dim3(6, 128), 512, 0, stream>>>(qkv, ao);
    attn_kernel<1><<<dim3(6, 128), 512, 0, stream>>>(qkv, ao);
    // x1 = x + ao @ Wo + bo   (bf16 out)
    gemm_kernel<1, 0, 1, 0, 1, 3><<<384, 512, 0, stream>>>(
        ao, woT, bo, x, x1, 32768, 384, 384);
    // h2 = LN(x1)
    ln_bf16_kernel<<<8192, 256, 0, stream>>>(x1, g2, be2, hbuf);
    // u = relu(h2 @ W1 + b1)
    gemm_kernel<1, 1, 0, 0, 1, 12><<<1536, 512, 0, stream>>>(
        hbuf, w1T, b1, nullptr, ubuf, 32768, 1536, 384);
    // out = x1 + u @ W2 + b2  (fp32 out, bf16 res)
    gemm_kernel<1, 0, 1, 1, 0, 3><<<384, 512, 0, stream>>>(
        ubuf, w2T, b2, x1, (float*)d_out, 32768, 384, 1536);
}